// Round 9
// baseline (22548.880 us; speedup 1.0000x reference)
//
#include <hip/hip_runtime.h>
#include <math.h>

#define B_ 16
#define T_ 64
#define N_ 512
#define H_ 128
#define P_ 12
#define NH 65536  // N_*H_

// ---------------------------------------------------------------------------
// Lx[b,t,m] = sum_n L[m,n] * x[b,t,n]   (L symmetric)
// ---------------------------------------------------------------------------
__global__ __launch_bounds__(512) void lx_kernel(const float* __restrict__ x,
                                                 const float* __restrict__ L,
                                                 float* __restrict__ Lx) {
    __shared__ __align__(16) float xs[4][N_];
    const int r0 = blockIdx.x * 4;
    const int tid = threadIdx.x;
    for (int j = 0; j < 4; ++j)
        xs[j][tid] = x[(size_t)(r0 + j) * N_ + tid];
    __syncthreads();
    float a0 = 0.f, a1 = 0.f, a2 = 0.f, a3 = 0.f;
    const int m = tid;
#pragma unroll 8
    for (int n = 0; n < N_; ++n) {
        float lv = L[(size_t)n * N_ + m];
        a0 += xs[0][n] * lv;
        a1 += xs[1][n] * lv;
        a2 += xs[2][n] * lv;
        a3 += xs[3][n] * lv;
    }
    Lx[(size_t)(r0 + 0) * N_ + m] = a0;
    Lx[(size_t)(r0 + 1) * N_ + m] = a1;
    Lx[(size_t)(r0 + 2) * N_ + m] = a2;
    Lx[(size_t)(r0 + 3) * N_ + m] = a3;
}

#define FMA4(dst, a, hv)                                                      \
    dst[0] += (a) * (hv).x; dst[1] += (a) * (hv).y;                           \
    dst[2] += (a) * (hv).z; dst[3] += (a) * (hv).w;

// ===========================================================================
// gc1: Z = L@Hprev ; ru = sigmoid(Z@W1[1:] + Lx*W1[0] + b1)
//      flat<65536 -> rh = ru*h ; else u = ru
// R9: 16-row tiles, grid 512 = mtile(32)x b(16), b = blockIdx&15.
//   CRITICAL: b must stay in the low 4 bits so XCD = blockIdx%8 = b%8 and each
//   batch's h/rh/u panels live in ONE XCD's L2 (R5 used b=blockIdx>>5 and got
//   cross-XCD misses: 299 MB FETCH, 100x slowdown).
// LDS 57.6 KB -> 2 blocks/CU (4 waves/SIMD) so the ~30 barriers of one block
// overlap the other block's compute (R8 was 1 block/CU, 2 waves/SIMD).
// NOTE: plain __launch_bounds__(512) — (512,4) forced 64 VGPRs + spill (R3).
// NOTE: W1 via LDS only; global-streamed W thrashed L2 (R3/R4).
// ===========================================================================
__global__ __launch_bounds__(512) void gc1_kernel(
    const float* __restrict__ L, const float* __restrict__ Hprev,
    const float* __restrict__ Lx, const float* __restrict__ W1,
    const float* __restrict__ b1, float* __restrict__ rh,
    float* __restrict__ u, int t) {
    __shared__ __align__(16) float Ht[2][32][H_];   // 32768 B
    union LW {
        float Lt[2][32][20];   // 5120 B, transposed [k][m], pitch 20 (b128-aligned)
        float Wt[16][260];     // 16640 B, phase-2 W chunk
    };
    __shared__ __align__(16) LW sm;
    __shared__ __align__(16) float Zb[16][H_];      // 8192 B  -> total 57600 B

    const int tid = threadIdx.x;
    const int b = blockIdx.x & 15;         // XCD-locality decode (see header)
    const int m0 = (blockIdx.x >> 4) * 16;
    const float* __restrict__ Hb = Hprev + (size_t)b * NH;

    // staging indices
    const int hrow = tid >> 5, hcol = (tid & 31) * 4;  // H: 2x16 rows x 128 cols
    const int lm = tid >> 5, lk = tid & 31;            // L: 16 m x 32 k (transposed)

    // ---- stage chunk 0
    {
        *(float4*)&Ht[0][hrow][hcol] = *(const float4*)&Hb[(size_t)hrow * H_ + hcol];
        *(float4*)&Ht[0][hrow + 16][hcol] =
            *(const float4*)&Hb[(size_t)(hrow + 16) * H_ + hcol];
        sm.Lt[0][lk][lm] = L[(size_t)(m0 + lm) * N_ + lk];
    }
    __syncthreads();

    // ---- phase 1: k-split x8; one wave covers full 16m x 128c tile per k.
    const int g = tid >> 6;          // wave 0..7
    const int l = tid & 63;
    const int ty = l >> 4;           // 0..3 -> m-quad ty*4
    const int tx = l & 15;           // 0..15 -> c-quads {tx*4, 64+tx*4}
    const int ma0 = ty * 4;
    const int ca0 = tx * 4, cb0 = 64 + tx * 4;

    float acc[4][2][4] = {};         // [m][c-half][c]

    for (int kc = 0; kc < 16; ++kc) {
        const int bi = kc & 1, bj = bi ^ 1;
        float4 p0, p1;
        float pl;
        if (kc < 15) {
            const size_t kb = (size_t)(kc + 1) * 32;
            p0 = *(const float4*)&Hb[(kb + hrow) * H_ + hcol];
            p1 = *(const float4*)&Hb[(kb + hrow + 16) * H_ + hcol];
            pl = L[(size_t)(m0 + lm) * N_ + kb + lk];
        }
#pragma unroll
        for (int kk = 0; kk < 4; ++kk) {
            const int k = g * 4 + kk;
            const float4 la = *(const float4*)&sm.Lt[bi][k][ma0];
            const float4 h0 = *(const float4*)&Ht[bi][k][ca0];
            const float4 h1 = *(const float4*)&Ht[bi][k][cb0];
            FMA4(acc[0][0], la.x, h0) FMA4(acc[0][1], la.x, h1)
            FMA4(acc[1][0], la.y, h0) FMA4(acc[1][1], la.y, h1)
            FMA4(acc[2][0], la.z, h0) FMA4(acc[2][1], la.z, h1)
            FMA4(acc[3][0], la.w, h0) FMA4(acc[3][1], la.w, h1)
        }
        if (kc < 15) {
            *(float4*)&Ht[bj][hrow][hcol] = p0;
            *(float4*)&Ht[bj][hrow + 16][hcol] = p1;
            sm.Lt[bj][lk][lm] = pl;
        }
        __syncthreads();
    }

    // ---- merge 8 k-partials (wave r adds; round 0 writes) — deterministic
    for (int r = 0; r < 8; ++r) {
        if (g == r) {
#pragma unroll
            for (int i = 0; i < 4; ++i) {
#pragma unroll
                for (int v = 0; v < 2; ++v) {
                    const int c = v ? cb0 : ca0;
                    float4* zp = (float4*)&Zb[ma0 + i][c];
                    if (r == 0) {
                        *zp = make_float4(acc[i][v][0], acc[i][v][1],
                                          acc[i][v][2], acc[i][v][3]);
                    } else {
                        float4 z = *zp;
                        *zp = make_float4(z.x + acc[i][v][0], z.y + acc[i][v][1],
                                          z.z + acc[i][v][2], z.w + acc[i][v][3]);
                    }
                }
            }
        }
        __syncthreads();
    }

    // ---- phase 2: out = Z @ W1[1:,:]  (W in LDS, 8 chunks of 16 ch)
    const int to = tid & 63, tm = tid >> 6;  // o0 in [0,256), 8 m-groups of 2
    const int o0 = to * 4;
    float a2[2][4] = {};
    const int wr = tid >> 5, wc = (tid & 31) * 4;

    for (int ck = 0; ck < 8; ++ck) {
        *(float4*)&sm.Wt[wr][wc] =
            *(const float4*)&W1[(size_t)(1 + ck * 16 + wr) * 256 + wc];
        *(float4*)&sm.Wt[wr][wc + 128] =
            *(const float4*)&W1[(size_t)(1 + ck * 16 + wr) * 256 + wc + 128];
        __syncthreads();
#pragma unroll
        for (int ch4 = 0; ch4 < 4; ++ch4) {
            const float4 w0v = *(const float4*)&sm.Wt[ch4 * 4 + 0][o0];
            const float4 w1v = *(const float4*)&sm.Wt[ch4 * 4 + 1][o0];
            const float4 w2v = *(const float4*)&sm.Wt[ch4 * 4 + 2][o0];
            const float4 w3v = *(const float4*)&sm.Wt[ch4 * 4 + 3][o0];
            const int cc = ck * 16 + ch4 * 4;
#pragma unroll
            for (int i = 0; i < 2; ++i) {
                const float4 zv = *(const float4*)&Zb[tm + 8 * i][cc];
                a2[i][0] += zv.x * w0v.x + zv.y * w1v.x + zv.z * w2v.x + zv.w * w3v.x;
                a2[i][1] += zv.x * w0v.y + zv.y * w1v.y + zv.z * w2v.y + zv.w * w3v.y;
                a2[i][2] += zv.x * w0v.z + zv.y * w1v.z + zv.z * w2v.z + zv.w * w3v.z;
                a2[i][3] += zv.x * w0v.w + zv.y * w1v.w + zv.z * w2v.w + zv.w * w3v.w;
            }
        }
        __syncthreads();
    }

    // ---- epilogue (verified structure; mi = tm + 8i covers rows 0..15)
    const float4 w0r = *(const float4*)&W1[o0];   // row 0 (x channel)
    const float4 bbv = *(const float4*)&b1[o0];
    const float* __restrict__ LxRow = Lx + ((size_t)b * T_ + t) * N_ + m0;
    float* __restrict__ rhB = rh + (size_t)b * NH;
    float* __restrict__ uB = u + (size_t)b * NH;
    const bool isR = (m0 < 256);   // 16-row tile never straddles the flat split
#pragma unroll
    for (int i = 0; i < 2; ++i) {
        const int mi = tm + 8 * i;
        const float lx = LxRow[mi];
        float v0 = a2[i][0] + lx * w0r.x + bbv.x;
        float v1 = a2[i][1] + lx * w0r.y + bbv.y;
        float v2 = a2[i][2] + lx * w0r.z + bbv.z;
        float v3 = a2[i][3] + lx * w0r.w + bbv.w;
        float s0 = 1.f / (1.f + expf(-v0));
        float s1 = 1.f / (1.f + expf(-v1));
        float s2 = 1.f / (1.f + expf(-v2));
        float s3 = 1.f / (1.f + expf(-v3));
        const int fl = (m0 + mi) * 256 + o0;
        if (isR) {
            float4 hv = *(const float4*)&Hb[fl];
            *(float4*)&rhB[fl] = make_float4(s0 * hv.x, s1 * hv.y, s2 * hv.z, s3 * hv.w);
        } else {
            *(float4*)&uB[fl - NH] = make_float4(s0, s1, s2, s3);
        }
    }
}

// ===========================================================================
// gc2: Z = L@rh ; c = tanh(Z@W2[1:] + Lx*W2[0] + b2) ; hn = u*h + (1-u)*c
//      hs1[b,t,m] = hn[m,:] . att_w1 + att_b1
// Same 16-row / 512-block structure as gc1; O=128. LDS 51456 B.
// ===========================================================================
__global__ __launch_bounds__(512) void gc2_kernel(
    const float* __restrict__ L, const float* __restrict__ Hprev,
    const float* __restrict__ rh, const float* __restrict__ u,
    const float* __restrict__ Lx, const float* __restrict__ W2,
    const float* __restrict__ b2, const float* __restrict__ aw1,
    const float* __restrict__ ab1, float* __restrict__ Hnew,
    float* __restrict__ hs1, int t) {
    __shared__ __align__(16) float Ht[2][32][H_];   // 32768 B
    union LW {
        float Lt[2][32][20];   // 5120 B
        float Wt[16][132];     // 8448 B
    };
    __shared__ __align__(16) LW sm;
    __shared__ __align__(16) float Zb[16][H_];      // 8192 B
    __shared__ __align__(16) float red[16][32];     // 2048 B  -> 51456 B

    const int tid = threadIdx.x;
    const int b = blockIdx.x & 15;
    const int m0 = (blockIdx.x >> 4) * 16;
    const float* __restrict__ Rb = rh + (size_t)b * NH;
    const float* __restrict__ Hb = Hprev + (size_t)b * NH;
    const float* __restrict__ Ub = u + (size_t)b * NH;

    const int hrow = tid >> 5, hcol = (tid & 31) * 4;
    const int lm = tid >> 5, lk = tid & 31;

    {
        *(float4*)&Ht[0][hrow][hcol] = *(const float4*)&Rb[(size_t)hrow * H_ + hcol];
        *(float4*)&Ht[0][hrow + 16][hcol] =
            *(const float4*)&Rb[(size_t)(hrow + 16) * H_ + hcol];
        sm.Lt[0][lk][lm] = L[(size_t)(m0 + lm) * N_ + lk];
    }
    __syncthreads();

    const int g = tid >> 6;
    const int l = tid & 63;
    const int ty = l >> 4;
    const int tx = l & 15;
    const int ma0 = ty * 4;
    const int ca0 = tx * 4, cb0 = 64 + tx * 4;

    float acc[4][2][4] = {};

    for (int kc = 0; kc < 16; ++kc) {
        const int bi = kc & 1, bj = bi ^ 1;
        float4 p0, p1;
        float pl;
        if (kc < 15) {
            const size_t kb = (size_t)(kc + 1) * 32;
            p0 = *(const float4*)&Rb[(kb + hrow) * H_ + hcol];
            p1 = *(const float4*)&Rb[(kb + hrow + 16) * H_ + hcol];
            pl = L[(size_t)(m0 + lm) * N_ + kb + lk];
        }
#pragma unroll
        for (int kk = 0; kk < 4; ++kk) {
            const int k = g * 4 + kk;
            const float4 la = *(const float4*)&sm.Lt[bi][k][ma0];
            const float4 h0 = *(const float4*)&Ht[bi][k][ca0];
            const float4 h1 = *(const float4*)&Ht[bi][k][cb0];
            FMA4(acc[0][0], la.x, h0) FMA4(acc[0][1], la.x, h1)
            FMA4(acc[1][0], la.y, h0) FMA4(acc[1][1], la.y, h1)
            FMA4(acc[2][0], la.z, h0) FMA4(acc[2][1], la.z, h1)
            FMA4(acc[3][0], la.w, h0) FMA4(acc[3][1], la.w, h1)
        }
        if (kc < 15) {
            *(float4*)&Ht[bj][hrow][hcol] = p0;
            *(float4*)&Ht[bj][hrow + 16][hcol] = p1;
            sm.Lt[bj][lk][lm] = pl;
        }
        __syncthreads();
    }

    for (int r = 0; r < 8; ++r) {
        if (g == r) {
#pragma unroll
            for (int i = 0; i < 4; ++i) {
#pragma unroll
                for (int v = 0; v < 2; ++v) {
                    const int c = v ? cb0 : ca0;
                    float4* zp = (float4*)&Zb[ma0 + i][c];
                    if (r == 0) {
                        *zp = make_float4(acc[i][v][0], acc[i][v][1],
                                          acc[i][v][2], acc[i][v][3]);
                    } else {
                        float4 z = *zp;
                        *zp = make_float4(z.x + acc[i][v][0], z.y + acc[i][v][1],
                                          z.z + acc[i][v][2], z.w + acc[i][v][3]);
                    }
                }
            }
        }
        __syncthreads();
    }

    // ---- phase 2: O=128, 1m x 4o per thread, W2 in LDS (8 chunks of 16 ch)
    const int to = tid & 31, tm = tid >> 5;   // 16 m-groups of 1
    const int o0 = to * 4;
    float a2[4] = {0.f, 0.f, 0.f, 0.f};
    const int wr = tid >> 5, wc = (tid & 31) * 4;

    for (int ck = 0; ck < 8; ++ck) {
        *(float4*)&sm.Wt[wr][wc] =
            *(const float4*)&W2[(size_t)(1 + ck * 16 + wr) * H_ + wc];
        __syncthreads();
#pragma unroll
        for (int ch4 = 0; ch4 < 4; ++ch4) {
            const float4 w0v = *(const float4*)&sm.Wt[ch4 * 4 + 0][o0];
            const float4 w1v = *(const float4*)&sm.Wt[ch4 * 4 + 1][o0];
            const float4 w2v = *(const float4*)&sm.Wt[ch4 * 4 + 2][o0];
            const float4 w3v = *(const float4*)&sm.Wt[ch4 * 4 + 3][o0];
            const int cc = ck * 16 + ch4 * 4;
            const float4 zv = *(const float4*)&Zb[tm][cc];
            a2[0] += zv.x * w0v.x + zv.y * w1v.x + zv.z * w2v.x + zv.w * w3v.x;
            a2[1] += zv.x * w0v.y + zv.y * w1v.y + zv.z * w2v.y + zv.w * w3v.y;
            a2[2] += zv.x * w0v.z + zv.y * w1v.z + zv.z * w2v.z + zv.w * w3v.z;
            a2[3] += zv.x * w0v.w + zv.y * w1v.w + zv.z * w2v.w + zv.w * w3v.w;
        }
        __syncthreads();
    }

    // ---- epilogue (verified structure; mi = tm covers rows 0..15)
    const float4 w0r = *(const float4*)&W2[o0];
    const float4 bbv = *(const float4*)&b2[o0];
    const float4 awv = *(const float4*)&aw1[o0];
    const float* __restrict__ LxRow = Lx + ((size_t)b * T_ + t) * N_ + m0;
    float* __restrict__ HnB = Hnew + (size_t)b * NH;
    {
        const int mi = tm;
        const float lx = LxRow[mi];
        float c0e = tanhf(a2[0] + lx * w0r.x + bbv.x);
        float c1e = tanhf(a2[1] + lx * w0r.y + bbv.y);
        float c2e = tanhf(a2[2] + lx * w0r.z + bbv.z);
        float c3e = tanhf(a2[3] + lx * w0r.w + bbv.w);
        const int fl = (m0 + mi) * H_ + o0;
        float4 uv = *(const float4*)&Ub[fl];
        float4 hp = *(const float4*)&Hb[fl];
        float h0 = uv.x * hp.x + (1.f - uv.x) * c0e;
        float h1 = uv.y * hp.y + (1.f - uv.y) * c1e;
        float h2 = uv.z * hp.z + (1.f - uv.z) * c2e;
        float h3 = uv.w * hp.w + (1.f - uv.w) * c3e;
        *(float4*)&HnB[fl] = make_float4(h0, h1, h2, h3);
        red[mi][to] = h0 * awv.x + h1 * awv.y + h2 * awv.z + h3 * awv.w;
    }
    __syncthreads();
    if (tid < 16) {
        float s = 0.f;
#pragma unroll
        for (int k2 = 0; k2 < 32; ++k2) s += red[tid][k2];
        hs1[((size_t)b * T_ + t) * N_ + m0 + tid] = s + ab1[0];
    }
}

// ---------------------------------------------------------------------------
// beta[b,t] = softmax_t( (hs1@aw2+ab2) * (hs1@aw3+ab3) )
// ---------------------------------------------------------------------------
__global__ __launch_bounds__(64) void att_beta_kernel(
    const float* __restrict__ hs1, const float* __restrict__ aw2,
    const float* __restrict__ aw3, const float* __restrict__ ab2,
    const float* __restrict__ ab3, float* __restrict__ beta) {
    const int b = blockIdx.x;
    const int t = threadIdx.x;
    const float* __restrict__ row = hs1 + ((size_t)b * T_ + t) * N_;
    float f = 0.f, g = 0.f;
    for (int n = 0; n < N_; n += 4) {
        float4 hv = *(const float4*)&row[n];
        float4 w2v = *(const float4*)&aw2[n];
        float4 w3v = *(const float4*)&aw3[n];
        f += hv.x * w2v.x + hv.y * w2v.y + hv.z * w2v.z + hv.w * w2v.w;
        g += hv.x * w3v.x + hv.y * w3v.y + hv.z * w3v.z + hv.w * w3v.w;
    }
    f += ab2[0];
    g += ab3[0];
    float s = f * g;
    float mx = s;
    for (int off = 32; off; off >>= 1) mx = fmaxf(mx, __shfl_xor(mx, off));
    float e = expf(s - mx);
    float sum = e;
    for (int off = 32; off; off >>= 1) sum += __shfl_xor(sum, off);
    beta[b * T_ + t] = e / sum;
}

// ---------------------------------------------------------------------------
// out[b,p,n] = b_out[p] + sum_t beta[b,t]*hs1[b,t,n]*W_out[t,p]
// ---------------------------------------------------------------------------
__global__ __launch_bounds__(256) void att_out_kernel(
    const float* __restrict__ hs1, const float* __restrict__ beta,
    const float* __restrict__ Wout, const float* __restrict__ bout,
    float* __restrict__ out) {
    __shared__ float bs[T_];
    __shared__ float ws[T_][P_];
    const int b = blockIdx.x;
    const int tid = threadIdx.x;
    if (tid < T_) bs[tid] = beta[b * T_ + tid];
    for (int i = tid; i < T_ * P_; i += 256) ws[i / P_][i % P_] = Wout[i];
    __syncthreads();
    for (int nn = 0; nn < 2; ++nn) {
        const int n = tid + nn * 256;
        float acc[P_];
#pragma unroll
        for (int p = 0; p < P_; ++p) acc[p] = bout[p];
        for (int t = 0; t < T_; ++t) {
            float v = bs[t] * hs1[((size_t)b * T_ + t) * N_ + n];
#pragma unroll
            for (int p = 0; p < P_; ++p) acc[p] += v * ws[t][p];
        }
#pragma unroll
        for (int p = 0; p < P_; ++p) out[((size_t)b * P_ + p) * N_ + n] = acc[p];
    }
}

extern "C" void kernel_launch(void* const* d_in, const int* in_sizes, int n_in,
                              void* d_out, int out_size, void* d_ws, size_t ws_size,
                              hipStream_t stream) {
    const float* x = (const float*)d_in[0];
    const float* L = (const float*)d_in[1];
    const float* W1 = (const float*)d_in[2];
    const float* b1 = (const float*)d_in[3];
    const float* W2 = (const float*)d_in[4];
    const float* b2 = (const float*)d_in[5];
    const float* aw1 = (const float*)d_in[6];
    const float* aw2 = (const float*)d_in[7];
    const float* aw3 = (const float*)d_in[8];
    const float* ab1 = (const float*)d_in[9];
    const float* ab2 = (const float*)d_in[10];
    const float* ab3 = (const float*)d_in[11];
    const float* Wout = (const float*)d_in[12];
    const float* bout = (const float*)d_in[13];
    float* out = (float*)d_out;

    float* ws = (float*)d_ws;
    float* Lx = ws;                      // B*T*N
    float* hs1 = Lx + B_ * T_ * N_;      // B*T*N
    float* hb0 = hs1 + B_ * T_ * N_;     // B*N*H
    float* hb1 = hb0 + (size_t)B_ * NH;  // B*N*H
    float* rh = hb1 + (size_t)B_ * NH;   // B*N*H
    float* u = rh + (size_t)B_ * NH;     // B*N*H
    float* beta = u + (size_t)B_ * NH;   // B*T
    (void)in_sizes; (void)n_in; (void)out_size; (void)ws_size;

    hipMemsetAsync(hb0, 0, (size_t)B_ * NH * sizeof(float), stream);
    lx_kernel<<<256, 512, 0, stream>>>(x, L, Lx);

    for (int t = 0; t < T_; ++t) {
        float* hp = (t & 1) ? hb1 : hb0;
        float* hn = (t & 1) ? hb0 : hb1;
        gc1_kernel<<<512, 512, 0, stream>>>(L, hp, Lx, W1, b1, rh, u, t);
        gc2_kernel<<<512, 512, 0, stream>>>(L, hp, rh, u, Lx, W2, b2, aw1, ab1,
                                            hn, hs1, t);
    }
    att_beta_kernel<<<16, 64, 0, stream>>>(hs1, aw2, aw3, ab2, ab3, beta);
    att_out_kernel<<<16, 256, 0, stream>>>(hs1, beta, Wout, bout, out);
}

// Round 10
// 3767.249 us; speedup vs baseline: 5.9855x; 5.9855x over previous
//
#include <hip/hip_runtime.h>
#include <math.h>

#define B_ 16
#define T_ 64
#define N_ 512
#define H_ 128
#define P_ 12
#define NH 65536  // N_*H_

// ---------------------------------------------------------------------------
// Lx[b,t,m] = sum_n L[m,n] * x[b,t,n]   (L symmetric)
// R10: 512 blocks x 2 rows (was 256x4 = 1 block/CU, latency-bound at 55 us).
// ---------------------------------------------------------------------------
__global__ __launch_bounds__(512) void lx_kernel(const float* __restrict__ x,
                                                 const float* __restrict__ L,
                                                 float* __restrict__ Lx) {
    __shared__ __align__(16) float xs[2][N_];
    const int r0 = blockIdx.x * 2;
    const int tid = threadIdx.x;
    for (int j = 0; j < 2; ++j)
        xs[j][tid] = x[(size_t)(r0 + j) * N_ + tid];
    __syncthreads();
    float a0 = 0.f, a1 = 0.f;
    const int m = tid;
#pragma unroll 8
    for (int n = 0; n < N_; ++n) {
        float lv = L[(size_t)n * N_ + m];
        a0 += xs[0][n] * lv;
        a1 += xs[1][n] * lv;
    }
    Lx[(size_t)(r0 + 0) * N_ + m] = a0;
    Lx[(size_t)(r0 + 1) * N_ + m] = a1;
}

#define FMA4(dst, a, hv)                                                      \
    dst[0] += (a) * (hv).x; dst[1] += (a) * (hv).y;                           \
    dst[2] += (a) * (hv).z; dst[3] += (a) * (hv).w;

// 64-FMA quad block for gc2 (R8 form)
#define FMAQ(u, v, A, Hv)                                                     \
    acc[u][0][v][0] += (A).x * (Hv).x; acc[u][0][v][1] += (A).x * (Hv).y;     \
    acc[u][0][v][2] += (A).x * (Hv).z; acc[u][0][v][3] += (A).x * (Hv).w;     \
    acc[u][1][v][0] += (A).y * (Hv).x; acc[u][1][v][1] += (A).y * (Hv).y;     \
    acc[u][1][v][2] += (A).y * (Hv).z; acc[u][1][v][3] += (A).y * (Hv).w;     \
    acc[u][2][v][0] += (A).z * (Hv).x; acc[u][2][v][1] += (A).z * (Hv).y;     \
    acc[u][2][v][2] += (A).z * (Hv).z; acc[u][2][v][3] += (A).z * (Hv).w;     \
    acc[u][3][v][0] += (A).w * (Hv).x; acc[u][3][v][1] += (A).w * (Hv).y;     \
    acc[u][3][v][2] += (A).w * (Hv).z; acc[u][3][v][3] += (A).w * (Hv).w;

// ===========================================================================
// gc1 — R9 version VERBATIM (512 blocks, 16-row tiles): measured 12 us timed,
// VGPR 64, FETCH 8.3 MB, no spill. DO NOT PERTURB (the near-identical gc2
// body at 512 blocks compiles to 128 VGPR + ~2 KB/thread scratch spill:
// 559 MB WRITE/dispatch, 28x slower — R5/R9).
// ===========================================================================
__global__ __launch_bounds__(512) void gc1_kernel(
    const float* __restrict__ L, const float* __restrict__ Hprev,
    const float* __restrict__ Lx, const float* __restrict__ W1,
    const float* __restrict__ b1, float* __restrict__ rh,
    float* __restrict__ u, int t) {
    __shared__ __align__(16) float Ht[2][32][H_];   // 32768 B
    union LW {
        float Lt[2][32][20];   // 5120 B, transposed [k][m], pitch 20
        float Wt[16][260];     // 16640 B, phase-2 W chunk
    };
    __shared__ __align__(16) LW sm;
    __shared__ __align__(16) float Zb[16][H_];      // 8192 B  -> total 57600 B

    const int tid = threadIdx.x;
    const int b = blockIdx.x & 15;         // XCD-locality decode
    const int m0 = (blockIdx.x >> 4) * 16;
    const float* __restrict__ Hb = Hprev + (size_t)b * NH;

    const int hrow = tid >> 5, hcol = (tid & 31) * 4;
    const int lm = tid >> 5, lk = tid & 31;

    {
        *(float4*)&Ht[0][hrow][hcol] = *(const float4*)&Hb[(size_t)hrow * H_ + hcol];
        *(float4*)&Ht[0][hrow + 16][hcol] =
            *(const float4*)&Hb[(size_t)(hrow + 16) * H_ + hcol];
        sm.Lt[0][lk][lm] = L[(size_t)(m0 + lm) * N_ + lk];
    }
    __syncthreads();

    const int g = tid >> 6;
    const int l = tid & 63;
    const int ty = l >> 4;
    const int tx = l & 15;
    const int ma0 = ty * 4;
    const int ca0 = tx * 4, cb0 = 64 + tx * 4;

    float acc[4][2][4] = {};

    for (int kc = 0; kc < 16; ++kc) {
        const int bi = kc & 1, bj = bi ^ 1;
        float4 p0, p1;
        float pl;
        if (kc < 15) {
            const size_t kb = (size_t)(kc + 1) * 32;
            p0 = *(const float4*)&Hb[(kb + hrow) * H_ + hcol];
            p1 = *(const float4*)&Hb[(kb + hrow + 16) * H_ + hcol];
            pl = L[(size_t)(m0 + lm) * N_ + kb + lk];
        }
#pragma unroll
        for (int kk = 0; kk < 4; ++kk) {
            const int k = g * 4 + kk;
            const float4 la = *(const float4*)&sm.Lt[bi][k][ma0];
            const float4 h0 = *(const float4*)&Ht[bi][k][ca0];
            const float4 h1 = *(const float4*)&Ht[bi][k][cb0];
            FMA4(acc[0][0], la.x, h0) FMA4(acc[0][1], la.x, h1)
            FMA4(acc[1][0], la.y, h0) FMA4(acc[1][1], la.y, h1)
            FMA4(acc[2][0], la.z, h0) FMA4(acc[2][1], la.z, h1)
            FMA4(acc[3][0], la.w, h0) FMA4(acc[3][1], la.w, h1)
        }
        if (kc < 15) {
            *(float4*)&Ht[bj][hrow][hcol] = p0;
            *(float4*)&Ht[bj][hrow + 16][hcol] = p1;
            sm.Lt[bj][lk][lm] = pl;
        }
        __syncthreads();
    }

    for (int r = 0; r < 8; ++r) {
        if (g == r) {
#pragma unroll
            for (int i = 0; i < 4; ++i) {
#pragma unroll
                for (int v = 0; v < 2; ++v) {
                    const int c = v ? cb0 : ca0;
                    float4* zp = (float4*)&Zb[ma0 + i][c];
                    if (r == 0) {
                        *zp = make_float4(acc[i][v][0], acc[i][v][1],
                                          acc[i][v][2], acc[i][v][3]);
                    } else {
                        float4 z = *zp;
                        *zp = make_float4(z.x + acc[i][v][0], z.y + acc[i][v][1],
                                          z.z + acc[i][v][2], z.w + acc[i][v][3]);
                    }
                }
            }
        }
        __syncthreads();
    }

    const int to = tid & 63, tm = tid >> 6;
    const int o0 = to * 4;
    float a2[2][4] = {};
    const int wr = tid >> 5, wc = (tid & 31) * 4;

    for (int ck = 0; ck < 8; ++ck) {
        *(float4*)&sm.Wt[wr][wc] =
            *(const float4*)&W1[(size_t)(1 + ck * 16 + wr) * 256 + wc];
        *(float4*)&sm.Wt[wr][wc + 128] =
            *(const float4*)&W1[(size_t)(1 + ck * 16 + wr) * 256 + wc + 128];
        __syncthreads();
#pragma unroll
        for (int ch4 = 0; ch4 < 4; ++ch4) {
            const float4 w0v = *(const float4*)&sm.Wt[ch4 * 4 + 0][o0];
            const float4 w1v = *(const float4*)&sm.Wt[ch4 * 4 + 1][o0];
            const float4 w2v = *(const float4*)&sm.Wt[ch4 * 4 + 2][o0];
            const float4 w3v = *(const float4*)&sm.Wt[ch4 * 4 + 3][o0];
            const int cc = ck * 16 + ch4 * 4;
#pragma unroll
            for (int i = 0; i < 2; ++i) {
                const float4 zv = *(const float4*)&Zb[tm + 8 * i][cc];
                a2[i][0] += zv.x * w0v.x + zv.y * w1v.x + zv.z * w2v.x + zv.w * w3v.x;
                a2[i][1] += zv.x * w0v.y + zv.y * w1v.y + zv.z * w2v.y + zv.w * w3v.y;
                a2[i][2] += zv.x * w0v.z + zv.y * w1v.z + zv.z * w2v.z + zv.w * w3v.z;
                a2[i][3] += zv.x * w0v.w + zv.y * w1v.w + zv.z * w2v.w + zv.w * w3v.w;
            }
        }
        __syncthreads();
    }

    const float4 w0r = *(const float4*)&W1[o0];
    const float4 bbv = *(const float4*)&b1[o0];
    const float* __restrict__ LxRow = Lx + ((size_t)b * T_ + t) * N_ + m0;
    float* __restrict__ rhB = rh + (size_t)b * NH;
    float* __restrict__ uB = u + (size_t)b * NH;
    const bool isR = (m0 < 256);
#pragma unroll
    for (int i = 0; i < 2; ++i) {
        const int mi = tm + 8 * i;
        const float lx = LxRow[mi];
        float v0 = a2[i][0] + lx * w0r.x + bbv.x;
        float v1 = a2[i][1] + lx * w0r.y + bbv.y;
        float v2 = a2[i][2] + lx * w0r.z + bbv.z;
        float v3 = a2[i][3] + lx * w0r.w + bbv.w;
        float s0 = 1.f / (1.f + expf(-v0));
        float s1 = 1.f / (1.f + expf(-v1));
        float s2 = 1.f / (1.f + expf(-v2));
        float s3 = 1.f / (1.f + expf(-v3));
        const int fl = (m0 + mi) * 256 + o0;
        if (isR) {
            float4 hv = *(const float4*)&Hb[fl];
            *(float4*)&rhB[fl] = make_float4(s0 * hv.x, s1 * hv.y, s2 * hv.z, s3 * hv.w);
        } else {
            *(float4*)&uB[fl - NH] = make_float4(s0, s1, s2, s3);
        }
    }
}

// ===========================================================================
// gc2 — R8 version VERBATIM (256 blocks, 32-row tiles, k-split x8):
// verified clean in R8 (no spill). The 512-block variants of this kernel
// body spill to scratch (R5/R9: 559 MB WRITE/dispatch) — keep at 256.
// ===========================================================================
__global__ __launch_bounds__(512) void gc2_kernel(
    const float* __restrict__ L, const float* __restrict__ Hprev,
    const float* __restrict__ rh, const float* __restrict__ u,
    const float* __restrict__ Lx, const float* __restrict__ W2,
    const float* __restrict__ b2, const float* __restrict__ aw1,
    const float* __restrict__ ab1, float* __restrict__ Hnew,
    float* __restrict__ hs1, int t) {
    __shared__ __align__(16) float Ht[2][32][H_];   // 32768 B
    union LW {
        float Lt[2][32][36];   // 9216 B
        float Wt[16][132];     // 8448 B
    };
    __shared__ __align__(16) LW sm;
    __shared__ __align__(16) float Zb[32][H_];      // 16384 B
    __shared__ __align__(16) float red[32][32];     //  4096 B

    const int tid = threadIdx.x;
    const int b = blockIdx.x & 15;
    const int m0 = (blockIdx.x >> 4) * 32;
    const float* __restrict__ Rb = rh + (size_t)b * NH;
    const float* __restrict__ Hb = Hprev + (size_t)b * NH;
    const float* __restrict__ Ub = u + (size_t)b * NH;

    const int hrow = tid >> 5, hcol = (tid & 31) * 4;
    const int lm = tid >> 4, lk0 = (tid & 15) * 2;

    {
        *(float4*)&Ht[0][hrow][hcol] = *(const float4*)&Rb[(size_t)hrow * H_ + hcol];
        *(float4*)&Ht[0][hrow + 16][hcol] =
            *(const float4*)&Rb[(size_t)(hrow + 16) * H_ + hcol];
        float2 lv = *(const float2*)&L[(size_t)(m0 + lm) * N_ + lk0];
        sm.Lt[0][lk0 + 0][lm] = lv.x;
        sm.Lt[0][lk0 + 1][lm] = lv.y;
    }
    __syncthreads();

    const int g = tid >> 6;
    const int l = tid & 63;
    const int ty = l >> 4;
    const int tx = l & 15;
    const int ma0 = ty * 4, mb0 = 16 + ty * 4;
    const int ca0 = tx * 4, cb0 = 64 + tx * 4;

    float acc[2][4][2][4] = {};

    for (int kc = 0; kc < 16; ++kc) {
        const int bi = kc & 1, bj = bi ^ 1;
        float4 p0, p1;
        float2 pl;
        if (kc < 15) {
            const size_t kb = (size_t)(kc + 1) * 32;
            p0 = *(const float4*)&Rb[(kb + hrow) * H_ + hcol];
            p1 = *(const float4*)&Rb[(kb + hrow + 16) * H_ + hcol];
            pl = *(const float2*)&L[(size_t)(m0 + lm) * N_ + kb + lk0];
        }
#pragma unroll
        for (int kk = 0; kk < 4; ++kk) {
            const int k = g * 4 + kk;
            const float4 la0 = *(const float4*)&sm.Lt[bi][k][ma0];
            const float4 la1 = *(const float4*)&sm.Lt[bi][k][mb0];
            const float4 h0 = *(const float4*)&Ht[bi][k][ca0];
            const float4 h1 = *(const float4*)&Ht[bi][k][cb0];
            FMAQ(0, 0, la0, h0)
            FMAQ(0, 1, la0, h1)
            FMAQ(1, 0, la1, h0)
            FMAQ(1, 1, la1, h1)
        }
        if (kc < 15) {
            *(float4*)&Ht[bj][hrow][hcol] = p0;
            *(float4*)&Ht[bj][hrow + 16][hcol] = p1;
            sm.Lt[bj][lk0 + 0][lm] = pl.x;
            sm.Lt[bj][lk0 + 1][lm] = pl.y;
        }
        __syncthreads();
    }

    for (int r = 0; r < 8; ++r) {
        if (g == r) {
#pragma unroll
            for (int uu = 0; uu < 2; ++uu)
#pragma unroll
                for (int i = 0; i < 4; ++i) {
                    const int m = uu * 16 + ty * 4 + i;
#pragma unroll
                    for (int v = 0; v < 2; ++v) {
                        const int c = v ? cb0 : ca0;
                        float4* zp = (float4*)&Zb[m][c];
                        if (r == 0) {
                            *zp = make_float4(acc[uu][i][v][0], acc[uu][i][v][1],
                                              acc[uu][i][v][2], acc[uu][i][v][3]);
                        } else {
                            float4 z = *zp;
                            *zp = make_float4(z.x + acc[uu][i][v][0],
                                              z.y + acc[uu][i][v][1],
                                              z.z + acc[uu][i][v][2],
                                              z.w + acc[uu][i][v][3]);
                        }
                    }
                }
        }
        __syncthreads();
    }

    // ---- phase 2: O=128, 2m x 4o per thread, W2 in LDS (8 chunks of 16 ch)
    const int to = tid & 31, tm = tid >> 5;   // 16 m-groups of 2
    const int o0 = to * 4;
    float a2[2][4] = {};
    const int wr = tid >> 5, wc = (tid & 31) * 4;

    for (int ck = 0; ck < 8; ++ck) {
        *(float4*)&sm.Wt[wr][wc] =
            *(const float4*)&W2[(size_t)(1 + ck * 16 + wr) * H_ + wc];
        __syncthreads();
#pragma unroll
        for (int ch4 = 0; ch4 < 4; ++ch4) {
            const float4 w0v = *(const float4*)&sm.Wt[ch4 * 4 + 0][o0];
            const float4 w1v = *(const float4*)&sm.Wt[ch4 * 4 + 1][o0];
            const float4 w2v = *(const float4*)&sm.Wt[ch4 * 4 + 2][o0];
            const float4 w3v = *(const float4*)&sm.Wt[ch4 * 4 + 3][o0];
            const int cc = ck * 16 + ch4 * 4;
#pragma unroll
            for (int i = 0; i < 2; ++i) {
                const float4 zv = *(const float4*)&Zb[tm + 16 * i][cc];
                a2[i][0] += zv.x * w0v.x + zv.y * w1v.x + zv.z * w2v.x + zv.w * w3v.x;
                a2[i][1] += zv.x * w0v.y + zv.y * w1v.y + zv.z * w2v.y + zv.w * w3v.y;
                a2[i][2] += zv.x * w0v.z + zv.y * w1v.z + zv.z * w2v.z + zv.w * w3v.z;
                a2[i][3] += zv.x * w0v.w + zv.y * w1v.w + zv.z * w2v.w + zv.w * w3v.w;
            }
        }
        __syncthreads();
    }

    // ---- epilogue (verified)
    const float4 w0r = *(const float4*)&W2[o0];
    const float4 bbv = *(const float4*)&b2[o0];
    const float4 awv = *(const float4*)&aw1[o0];
    const float* __restrict__ LxRow = Lx + ((size_t)b * T_ + t) * N_ + m0;
    float* __restrict__ HnB = Hnew + (size_t)b * NH;
#pragma unroll
    for (int i = 0; i < 2; ++i) {
        const int mi = tm + 16 * i;
        const float lx = LxRow[mi];
        float c0e = tanhf(a2[i][0] + lx * w0r.x + bbv.x);
        float c1e = tanhf(a2[i][1] + lx * w0r.y + bbv.y);
        float c2e = tanhf(a2[i][2] + lx * w0r.z + bbv.z);
        float c3e = tanhf(a2[i][3] + lx * w0r.w + bbv.w);
        const int fl = (m0 + mi) * H_ + o0;
        float4 uv = *(const float4*)&Ub[fl];
        float4 hp = *(const float4*)&Hb[fl];
        float h0 = uv.x * hp.x + (1.f - uv.x) * c0e;
        float h1 = uv.y * hp.y + (1.f - uv.y) * c1e;
        float h2 = uv.z * hp.z + (1.f - uv.z) * c2e;
        float h3 = uv.w * hp.w + (1.f - uv.w) * c3e;
        *(float4*)&HnB[fl] = make_float4(h0, h1, h2, h3);
        red[mi][to] = h0 * awv.x + h1 * awv.y + h2 * awv.z + h3 * awv.w;
    }
    __syncthreads();
    if (tid < 32) {
        float s = 0.f;
#pragma unroll
        for (int k2 = 0; k2 < 32; ++k2) s += red[tid][k2];
        hs1[((size_t)b * T_ + t) * N_ + m0 + tid] = s + ab1[0];
    }
}

// ---------------------------------------------------------------------------
// beta[b,t] = softmax_t( (hs1@aw2+ab2) * (hs1@aw3+ab3) )
// ---------------------------------------------------------------------------
__global__ __launch_bounds__(64) void att_beta_kernel(
    const float* __restrict__ hs1, const float* __restrict__ aw2,
    const float* __restrict__ aw3, const float* __restrict__ ab2,
    const float* __restrict__ ab3, float* __restrict__ beta) {
    const int b = blockIdx.x;
    const int t = threadIdx.x;
    const float* __restrict__ row = hs1 + ((size_t)b * T_ + t) * N_;
    float f = 0.f, g = 0.f;
    for (int n = 0; n < N_; n += 4) {
        float4 hv = *(const float4*)&row[n];
        float4 w2v = *(const float4*)&aw2[n];
        float4 w3v = *(const float4*)&aw3[n];
        f += hv.x * w2v.x + hv.y * w2v.y + hv.z * w2v.z + hv.w * w2v.w;
        g += hv.x * w3v.x + hv.y * w3v.y + hv.z * w3v.z + hv.w * w3v.w;
    }
    f += ab2[0];
    g += ab3[0];
    float s = f * g;
    float mx = s;
    for (int off = 32; off; off >>= 1) mx = fmaxf(mx, __shfl_xor(mx, off));
    float e = expf(s - mx);
    float sum = e;
    for (int off = 32; off; off >>= 1) sum += __shfl_xor(sum, off);
    beta[b * T_ + t] = e / sum;
}

// ---------------------------------------------------------------------------
// out[b,p,n] = b_out[p] + sum_t beta[b,t]*hs1[b,t,n]*W_out[t,p]
// ---------------------------------------------------------------------------
__global__ __launch_bounds__(256) void att_out_kernel(
    const float* __restrict__ hs1, const float* __restrict__ beta,
    const float* __restrict__ Wout, const float* __restrict__ bout,
    float* __restrict__ out) {
    __shared__ float bs[T_];
    __shared__ float ws[T_][P_];
    const int b = blockIdx.x;
    const int tid = threadIdx.x;
    if (tid < T_) bs[tid] = beta[b * T_ + tid];
    for (int i = tid; i < T_ * P_; i += 256) ws[i / P_][i % P_] = Wout[i];
    __syncthreads();
    for (int nn = 0; nn < 2; ++nn) {
        const int n = tid + nn * 256;
        float acc[P_];
#pragma unroll
        for (int p = 0; p < P_; ++p) acc[p] = bout[p];
        for (int t = 0; t < T_; ++t) {
            float v = bs[t] * hs1[((size_t)b * T_ + t) * N_ + n];
#pragma unroll
            for (int p = 0; p < P_; ++p) acc[p] += v * ws[t][p];
        }
#pragma unroll
        for (int p = 0; p < P_; ++p) out[((size_t)b * P_ + p) * N_ + n] = acc[p];
    }
}

extern "C" void kernel_launch(void* const* d_in, const int* in_sizes, int n_in,
                              void* d_out, int out_size, void* d_ws, size_t ws_size,
                              hipStream_t stream) {
    const float* x = (const float*)d_in[0];
    const float* L = (const float*)d_in[1];
    const float* W1 = (const float*)d_in[2];
    const float* b1 = (const float*)d_in[3];
    const float* W2 = (const float*)d_in[4];
    const float* b2 = (const float*)d_in[5];
    const float* aw1 = (const float*)d_in[6];
    const float* aw2 = (const float*)d_in[7];
    const float* aw3 = (const float*)d_in[8];
    const float* ab1 = (const float*)d_in[9];
    const float* ab2 = (const float*)d_in[10];
    const float* ab3 = (const float*)d_in[11];
    const float* Wout = (const float*)d_in[12];
    const float* bout = (const float*)d_in[13];
    float* out = (float*)d_out;

    float* ws = (float*)d_ws;
    float* Lx = ws;                      // B*T*N
    float* hs1 = Lx + B_ * T_ * N_;      // B*T*N
    float* hb0 = hs1 + B_ * T_ * N_;     // B*N*H
    float* hb1 = hb0 + (size_t)B_ * NH;  // B*N*H
    float* rh = hb1 + (size_t)B_ * NH;   // B*N*H
    float* u = rh + (size_t)B_ * NH;     // B*N*H
    float* beta = u + (size_t)B_ * NH;   // B*T
    (void)in_sizes; (void)n_in; (void)out_size; (void)ws_size;

    hipMemsetAsync(hb0, 0, (size_t)B_ * NH * sizeof(float), stream);
    lx_kernel<<<512, 512, 0, stream>>>(x, L, Lx);

    for (int t = 0; t < T_; ++t) {
        float* hp = (t & 1) ? hb1 : hb0;
        float* hn = (t & 1) ? hb0 : hb1;
        gc1_kernel<<<512, 512, 0, stream>>>(L, hp, Lx, W1, b1, rh, u, t);
        gc2_kernel<<<256, 512, 0, stream>>>(L, hp, rh, u, Lx, W2, b2, aw1, ab1,
                                            hn, hs1, t);
    }
    att_beta_kernel<<<16, 64, 0, stream>>>(hs1, aw2, aw3, ab2, ab3, beta);
    att_out_kernel<<<16, 256, 0, stream>>>(hs1, beta, Wout, bout, out);
}